// Round 2
// baseline (374.707 us; speedup 1.0000x reference)
//
#include <hip/hip_runtime.h>

#define L 256
#define BATCH 512
#define CIN 32
#define RNNIN 64
#define HIDN 128
#define OUTN 512

// ws layout (floats):
//   Wc     @ 0        (128*32 = 4096)   Wc[j*32+c] = sum_m W_ih[j][m]*W_in[m][c]
//   bpre   @ 4096     (128)             b_ih + b_hh + W_ih@b_in
//   hs     @ 8192     (256*512*128)     hs[t*65536 + b*128 + j]
//   pooled @ 8192+16777216 (512*128)

__global__ __launch_bounds__(128) void prep_kernel(
    const float* __restrict__ W_in, const float* __restrict__ b_in,
    const float* __restrict__ W_ih, const float* __restrict__ b_ih,
    const float* __restrict__ b_hh,
    float* __restrict__ Wc, float* __restrict__ bpre)
{
    const int j = threadIdx.x;  // 128 threads, one per hidden unit
    float acc[CIN];
#pragma unroll
    for (int c = 0; c < CIN; ++c) acc[c] = 0.f;
    float bs = b_ih[j] + b_hh[j];
    for (int m = 0; m < RNNIN; ++m) {
        float w = W_ih[j * RNNIN + m];
        bs += w * b_in[m];
#pragma unroll
        for (int c = 0; c < CIN; ++c) acc[c] += w * W_in[m * CIN + c];
    }
#pragma unroll
    for (int c = 0; c < CIN; ++c) Wc[j * CIN + c] = acc[c];
    bpre[j] = bs;
}

// One block = 2 batch rows. thread (r = tid>>7, j = tid&127) computes h[r][j].
// W_hh row j held in registers (launch_bounds(256,1) frees the VGPR budget —
// without min-waves=1 the compiler capped at 96 VGPRs and demoted whh[]).
// h and x_t double-buffered in LDS (1 barrier/step). 4 independent
// accumulators break the serial FMA dependency chain.
__global__ __launch_bounds__(256, 1) void rnn_kernel(
    const float* __restrict__ x, const float* __restrict__ h0,
    const float* __restrict__ Whh,
    const float* __restrict__ Wc, const float* __restrict__ bpre,
    float* __restrict__ hs)
{
    const int tid = threadIdx.x;
    const int j = tid & 127;
    const int r = tid >> 7;
    const int b = blockIdx.x * 2 + r;

    float whh[HIDN];
#pragma unroll
    for (int k = 0; k < HIDN; k += 4) {
        float4 v = *(const float4*)(Whh + j * HIDN + k);
        whh[k] = v.x; whh[k + 1] = v.y; whh[k + 2] = v.z; whh[k + 3] = v.w;
    }
    float wc[CIN];
#pragma unroll
    for (int c = 0; c < CIN; c += 4) {
        float4 v = *(const float4*)(Wc + j * CIN + c);
        wc[c] = v.x; wc[c + 1] = v.y; wc[c + 2] = v.z; wc[c + 3] = v.w;
    }
    const float bp = bpre[j];

    __shared__ float hbuf[2][2][HIDN];  // [phase][row][k]
    __shared__ float xbuf[2][2][CIN];   // [phase][row][c]

    hbuf[0][r][j] = h0[b * HIDN + j];
    const int lrr = tid >> 5;   // loader role (tid<64): row
    const int lcc = tid & 31;   // loader role: channel
    const float* xptr = x + (size_t)(blockIdx.x * 2 + lrr) * (CIN * L) + lcc * L;
    if (tid < 64) xbuf[0][lrr][lcc] = xptr[0];
    __syncthreads();

    float* hsp = hs + b * HIDN + j;
    for (int t = 0; t < L; ++t) {
        const int p = t & 1;
        float xn = 0.f;
        if (tid < 64 && t < L - 1) xn = xptr[t + 1];  // prefetch next x_t

        float a0 = bp, a1 = 0.f, a2 = 0.f, a3 = 0.f;
#pragma unroll
        for (int c = 0; c < CIN; c += 16) {  // 2 iters, 4 b128 reads each
            float4 x0 = *(const float4*)(&xbuf[p][r][c]);
            float4 x1 = *(const float4*)(&xbuf[p][r][c + 4]);
            float4 x2 = *(const float4*)(&xbuf[p][r][c + 8]);
            float4 x3 = *(const float4*)(&xbuf[p][r][c + 12]);
            a0 += x0.x * wc[c]      + x0.y * wc[c + 1]  + x0.z * wc[c + 2]  + x0.w * wc[c + 3];
            a1 += x1.x * wc[c + 4]  + x1.y * wc[c + 5]  + x1.z * wc[c + 6]  + x1.w * wc[c + 7];
            a2 += x2.x * wc[c + 8]  + x2.y * wc[c + 9]  + x2.z * wc[c + 10] + x2.w * wc[c + 11];
            a3 += x3.x * wc[c + 12] + x3.y * wc[c + 13] + x3.z * wc[c + 14] + x3.w * wc[c + 15];
        }
#pragma unroll
        for (int k = 0; k < HIDN; k += 16) {  // 8 iters, 4 b128 reads each
            float4 h0v = *(const float4*)(&hbuf[p][r][k]);
            float4 h1v = *(const float4*)(&hbuf[p][r][k + 4]);
            float4 h2v = *(const float4*)(&hbuf[p][r][k + 8]);
            float4 h3v = *(const float4*)(&hbuf[p][r][k + 12]);
            a0 += h0v.x * whh[k]      + h0v.y * whh[k + 1]  + h0v.z * whh[k + 2]  + h0v.w * whh[k + 3];
            a1 += h1v.x * whh[k + 4]  + h1v.y * whh[k + 5]  + h1v.z * whh[k + 6]  + h1v.w * whh[k + 7];
            a2 += h2v.x * whh[k + 8]  + h2v.y * whh[k + 9]  + h2v.z * whh[k + 10] + h2v.w * whh[k + 11];
            a3 += h3v.x * whh[k + 12] + h3v.y * whh[k + 13] + h3v.z * whh[k + 14] + h3v.w * whh[k + 15];
        }
        float acc = (a0 + a1) + (a2 + a3);
        // tanh(x) = 1 - 2/(exp(2x)+1)  (stable at both extremes)
        float e = __expf(2.f * acc);
        float hn = 1.f - 2.f / (e + 1.f);

        hsp[(size_t)t * (BATCH * HIDN)] = hn;
        hbuf[p ^ 1][r][j] = hn;
        if (tid < 64 && t < L - 1) xbuf[p ^ 1][lrr][lcc] = xn;
        __syncthreads();  // step t writes (phase p^1) visible before step t+1 reads
    }
}

// Upsample 16x16 -> 32x32 (align_corners) + hardswish + mean, fused.
// Block handles (b, 32 hidden units); map staged in LDS.
__global__ __launch_bounds__(256) void pool_kernel(
    const float* __restrict__ hs, float* __restrict__ pooled)
{
    const int b = blockIdx.x >> 2;
    const int j0 = (blockIdx.x & 3) * 32;
    __shared__ float m[L][32];  // [t=y*16+x][j_off]; <=2-way conflicts (free)
    const float* src = hs + b * HIDN + j0;
    for (int idx = threadIdx.x; idx < L * 32; idx += 256) {
        int jo = idx & 31, t = idx >> 5;
        m[t][jo] = src[(size_t)t * (BATCH * HIDN) + jo];
    }
    __syncthreads();
    const int jo = threadIdx.x & 31;
    const int sub = threadIdx.x >> 5;  // 8 threads per j
    float acc = 0.f;
#pragma unroll 4
    for (int p = sub; p < 1024; p += 8) {
        int oy = p >> 5, ox = p & 31;
        float ysf = oy * (15.f / 31.f);
        int y0 = (int)ysf; float wy = ysf - (float)y0; int y1 = min(y0 + 1, 15);
        float xsf = ox * (15.f / 31.f);
        int x0 = (int)xsf; float wx = xsf - (float)x0; int x1 = min(x0 + 1, 15);
        float v00 = m[y0 * 16 + x0][jo], v01 = m[y0 * 16 + x1][jo];
        float v10 = m[y1 * 16 + x0][jo], v11 = m[y1 * 16 + x1][jo];
        float v0 = v00 + wx * (v01 - v00);
        float v1 = v10 + wx * (v11 - v10);
        float v = v0 + wy * (v1 - v0);
        float t6 = fminf(fmaxf(v + 3.f, 0.f), 6.f);
        acc += v * t6;
    }
    __shared__ float ps[8][32];
    ps[sub][jo] = acc;
    __syncthreads();
    if (threadIdx.x < 32) {
        float s = 0.f;
#pragma unroll
        for (int u = 0; u < 8; ++u) s += ps[u][threadIdx.x];
        pooled[b * HIDN + j0 + threadIdx.x] = s * (1.f / 6144.f);  // /6 hardswish, /1024 mean
    }
}

__global__ __launch_bounds__(256) void out_kernel(
    const float* __restrict__ pooled, const float* __restrict__ W_out,
    const float* __restrict__ b_out, float* __restrict__ out)
{
    const int b = blockIdx.x;
    __shared__ float pv[HIDN];
    if (threadIdx.x < HIDN) pv[threadIdx.x] = pooled[b * HIDN + threadIdx.x];
    __syncthreads();
    for (int o = threadIdx.x; o < OUTN; o += 256) {
        float acc = b_out[o];
#pragma unroll 8
        for (int k = 0; k < HIDN; k += 4) {
            float4 w = *(const float4*)(W_out + o * HIDN + k);
            acc += w.x * pv[k] + w.y * pv[k + 1] + w.z * pv[k + 2] + w.w * pv[k + 3];
        }
        out[b * OUTN + o] = acc;
    }
}

extern "C" void kernel_launch(void* const* d_in, const int* in_sizes, int n_in,
                              void* d_out, int out_size, void* d_ws, size_t ws_size,
                              hipStream_t stream)
{
    const float* x     = (const float*)d_in[0];
    const float* h0    = (const float*)d_in[1];
    const float* W_in  = (const float*)d_in[2];
    const float* b_in  = (const float*)d_in[3];
    const float* W_ih  = (const float*)d_in[4];
    const float* b_ih  = (const float*)d_in[5];
    const float* W_hh  = (const float*)d_in[6];
    const float* b_hh  = (const float*)d_in[7];
    const float* W_out = (const float*)d_in[8];
    const float* b_out = (const float*)d_in[9];
    float* out = (float*)d_out;

    float* ws     = (float*)d_ws;
    float* Wc     = ws;                      // 4096 floats
    float* bpre   = ws + 4096;               // 128 floats
    float* hs     = ws + 8192;               // 16,777,216 floats (64 MB)
    float* pooled = ws + 8192 + 16777216;    // 65,536 floats

    prep_kernel<<<1, 128, 0, stream>>>(W_in, b_in, W_ih, b_ih, b_hh, Wc, bpre);
    rnn_kernel<<<256, 256, 0, stream>>>(x, h0, W_hh, Wc, bpre, hs);
    pool_kernel<<<2048, 256, 0, stream>>>(hs, pooled);
    out_kernel<<<512, 256, 0, stream>>>(pooled, W_out, b_out, out);
}

// Round 3
// 322.054 us; speedup vs baseline: 1.1635x; 1.1635x over previous
//
#include <hip/hip_runtime.h>

#define L 256
#define BATCH 512
#define CIN 32
#define RNNIN 64
#define HIDN 128
#define OUTN 512

// ws layout (floats):
//   Wc     @ 0        (128*32 = 4096)   Wc[j*32+c] = sum_m W_ih[j][m]*W_in[m][c]
//   bpre   @ 4096     (128)             b_ih + b_hh + W_ih@b_in
//   hs     @ 8192     (256*512*128)     hs[t*65536 + b*128 + j]
//   pooled @ 8192+16777216 (512*128)

__global__ __launch_bounds__(128) void prep_kernel(
    const float* __restrict__ W_in, const float* __restrict__ b_in,
    const float* __restrict__ W_ih, const float* __restrict__ b_ih,
    const float* __restrict__ b_hh,
    float* __restrict__ Wc, float* __restrict__ bpre)
{
    const int j = threadIdx.x;
    float acc[CIN];
#pragma unroll
    for (int c = 0; c < CIN; ++c) acc[c] = 0.f;
    float bs = b_ih[j] + b_hh[j];
    for (int m = 0; m < RNNIN; ++m) {
        float w = W_ih[j * RNNIN + m];
        bs += w * b_in[m];
#pragma unroll
        for (int c = 0; c < CIN; ++c) acc[c] += w * W_in[m * CIN + c];
    }
#pragma unroll
    for (int c = 0; c < CIN; ++c) Wc[j * CIN + c] = acc[c];
    bpre[j] = bs;
}

// Cross-lane reduce helpers: xor1/xor2 via DPP quad_perm (VALU pipe, free),
// xor4 via ds_swizzle (1 LDS-pipe inst).
template <int CTRL>
__device__ __forceinline__ float dpp_add(float v) {
    int sw = __builtin_amdgcn_mov_dpp(__float_as_int(v), CTRL, 0xF, 0xF, true);
    return v + __int_as_float(sw);
}
__device__ __forceinline__ float swz_add_xor4(float v) {
    int sw = __builtin_amdgcn_ds_swizzle(__float_as_int(v), 0x101F);  // xor lane^4
    return v + __int_as_float(sw);
}
#define DPP_XOR1 0xB1  // quad_perm(1,0,3,2)
#define DPP_XOR2 0x4E  // quad_perm(2,3,0,1)

// One block = 1 batch row, 512 threads (8 waves). Thread = (jg, s):
//   s = tid&7 : k-split, covers h-k in [16s,16s+16) and x-c in [4s,4s+4)
//   jg = tid>>3 : output pair j0=2jg, j1=2jg+1
// Weights: 10 NAMED float4 (40 floats) -> guaranteed VGPR residency (the
// R0/R1 float whh[128] alloca was never promoted -> scratch; that plus
// 4B-LDS-per-MAC made the old kernel LDS/scratch bound at 240us).
// h chunks read in rotated order c_i = ((s>>1)+i)&3 -> provably
// bank-conflict-free across the 8 s-streams.
__global__ __launch_bounds__(512, 4) void rnn_kernel(
    const float* __restrict__ x, const float* __restrict__ h0,
    const float* __restrict__ Whh,
    const float* __restrict__ Wc, const float* __restrict__ bpre,
    float* __restrict__ hs)
{
    const int tid = threadIdx.x;
    const int s = tid & 7;
    const int jg = tid >> 3;
    const int j0 = jg * 2, j1 = j0 + 1;
    const int b = blockIdx.x;

    const int c0i = (s >> 1) & 3;
    const int c1i = (c0i + 1) & 3;
    const int c2i = (c0i + 2) & 3;
    const int c3i = (c0i + 3) & 3;

    const float* w0p = Whh + j0 * HIDN + s * 16;
    const float* w1p = Whh + j1 * HIDN + s * 16;
    float4 a0 = *(const float4*)(w0p + 4 * c0i);
    float4 a1 = *(const float4*)(w0p + 4 * c1i);
    float4 a2 = *(const float4*)(w0p + 4 * c2i);
    float4 a3 = *(const float4*)(w0p + 4 * c3i);
    float4 e0 = *(const float4*)(w1p + 4 * c0i);
    float4 e1 = *(const float4*)(w1p + 4 * c1i);
    float4 e2 = *(const float4*)(w1p + 4 * c2i);
    float4 e3 = *(const float4*)(w1p + 4 * c3i);
    float4 g0 = *(const float4*)(Wc + j0 * CIN + s * 4);
    float4 g1 = *(const float4*)(Wc + j1 * CIN + s * 4);
    const float bp0 = bpre[j0], bp1 = bpre[j1];

    __shared__ float hbuf[2][HIDN];
    __shared__ float xbuf[2][CIN];

    if (tid < HIDN) hbuf[0][tid] = h0[b * HIDN + tid];
    const float* xptr = x + (size_t)b * (CIN * L);
    if (tid < CIN) xbuf[0][tid] = xptr[tid * L];
    __syncthreads();

    float* hsp = hs + (size_t)b * HIDN;
#pragma unroll 2
    for (int t = 0; t < L; ++t) {
        const int p = t & 1;
        float xn = 0.f;
        if (tid < CIN) {
            int tn = (t + 1 < L) ? t + 1 : t;
            xn = xptr[tid * L + tn];  // prefetch next x_t (hidden by step)
        }

        const float* hb = &hbuf[p][s * 16];
        float4 h0v = *(const float4*)(hb + 4 * c0i);
        float4 h1v = *(const float4*)(hb + 4 * c1i);
        float4 h2v = *(const float4*)(hb + 4 * c2i);
        float4 h3v = *(const float4*)(hb + 4 * c3i);
        float4 xv  = *(const float4*)(&xbuf[p][s * 4]);

        float acc0 = a0.x * h0v.x + a0.y * h0v.y + a0.z * h0v.z + a0.w * h0v.w
                   + a1.x * h1v.x + a1.y * h1v.y + a1.z * h1v.z + a1.w * h1v.w
                   + a2.x * h2v.x + a2.y * h2v.y + a2.z * h2v.z + a2.w * h2v.w
                   + a3.x * h3v.x + a3.y * h3v.y + a3.z * h3v.z + a3.w * h3v.w
                   + g0.x * xv.x  + g0.y * xv.y  + g0.z * xv.z  + g0.w * xv.w;
        float acc1 = e0.x * h0v.x + e0.y * h0v.y + e0.z * h0v.z + e0.w * h0v.w
                   + e1.x * h1v.x + e1.y * h1v.y + e1.z * h1v.z + e1.w * h1v.w
                   + e2.x * h2v.x + e2.y * h2v.y + e2.z * h2v.z + e2.w * h2v.w
                   + e3.x * h3v.x + e3.y * h3v.y + e3.z * h3v.z + e3.w * h3v.w
                   + g1.x * xv.x  + g1.y * xv.y  + g1.z * xv.z  + g1.w * xv.w;

        // reduce over the 8 s-lanes (aligned groups): xor1, xor2 (DPP), xor4 (swizzle)
        acc0 = dpp_add<DPP_XOR1>(acc0);
        acc1 = dpp_add<DPP_XOR1>(acc1);
        acc0 = dpp_add<DPP_XOR2>(acc0);
        acc1 = dpp_add<DPP_XOR2>(acc1);
        acc0 = swz_add_xor4(acc0);
        acc1 = swz_add_xor4(acc1);

        float pre0 = acc0 + bp0, pre1 = acc1 + bp1;
        // tanh(x) = 1 - 2/(exp(2x)+1)
        float ea = __expf(2.f * pre0);
        float eb = __expf(2.f * pre1);
        float hn0 = 1.f - 2.f / (ea + 1.f);
        float hn1 = 1.f - 2.f / (eb + 1.f);

        if (s == 0) {
            hbuf[p ^ 1][j0] = hn0;
            hbuf[p ^ 1][j1] = hn1;
            *(float2*)(hsp + (size_t)t * (BATCH * HIDN) + j0) = make_float2(hn0, hn1);
        }
        if (tid < CIN) xbuf[p ^ 1][tid] = xn;
        __syncthreads();
    }
}

// Upsample 16x16 -> 32x32 (align_corners) + hardswish + mean, fused.
__global__ __launch_bounds__(256) void pool_kernel(
    const float* __restrict__ hs, float* __restrict__ pooled)
{
    const int b = blockIdx.x >> 2;
    const int j0 = (blockIdx.x & 3) * 32;
    __shared__ float m[L][32];
    // float4 staging: 2048 vec4 loads spread over 256 threads
    for (int i = threadIdx.x; i < L * 8; i += 256) {
        int jo4 = i & 7, t = i >> 3;
        *(float4*)&m[t][jo4 * 4] =
            *(const float4*)(hs + (size_t)t * (BATCH * HIDN) + b * HIDN + j0 + jo4 * 4);
    }
    __syncthreads();
    const int jo = threadIdx.x & 31;
    const int sub = threadIdx.x >> 5;  // 8 threads per j
    float acc = 0.f;
#pragma unroll 4
    for (int p = sub; p < 1024; p += 8) {
        int oy = p >> 5, ox = p & 31;
        float ysf = oy * (15.f / 31.f);
        int y0 = (int)ysf; float wy = ysf - (float)y0; int y1 = min(y0 + 1, 15);
        float xsf = ox * (15.f / 31.f);
        int x0 = (int)xsf; float wx = xsf - (float)x0; int x1 = min(x0 + 1, 15);
        float v00 = m[y0 * 16 + x0][jo], v01 = m[y0 * 16 + x1][jo];
        float v10 = m[y1 * 16 + x0][jo], v11 = m[y1 * 16 + x1][jo];
        float v0 = v00 + wx * (v01 - v00);
        float v1 = v10 + wx * (v11 - v10);
        float v = v0 + wy * (v1 - v0);
        float t6 = fminf(fmaxf(v + 3.f, 0.f), 6.f);
        acc += v * t6;
    }
    __shared__ float ps[8][32];
    ps[sub][jo] = acc;
    __syncthreads();
    if (threadIdx.x < 32) {
        float sum = 0.f;
#pragma unroll
        for (int u = 0; u < 8; ++u) sum += ps[u][threadIdx.x];
        pooled[b * HIDN + j0 + threadIdx.x] = sum * (1.f / 6144.f);
    }
}

__global__ __launch_bounds__(256) void out_kernel(
    const float* __restrict__ pooled, const float* __restrict__ W_out,
    const float* __restrict__ b_out, float* __restrict__ out)
{
    const int b = blockIdx.x;
    __shared__ float pv[HIDN];
    if (threadIdx.x < HIDN) pv[threadIdx.x] = pooled[b * HIDN + threadIdx.x];
    __syncthreads();
    for (int o = threadIdx.x; o < OUTN; o += 256) {
        float acc = b_out[o];
#pragma unroll 8
        for (int k = 0; k < HIDN; k += 4) {
            float4 w = *(const float4*)(W_out + o * HIDN + k);
            acc += w.x * pv[k] + w.y * pv[k + 1] + w.z * pv[k + 2] + w.w * pv[k + 3];
        }
        out[b * OUTN + o] = acc;
    }
}

extern "C" void kernel_launch(void* const* d_in, const int* in_sizes, int n_in,
                              void* d_out, int out_size, void* d_ws, size_t ws_size,
                              hipStream_t stream)
{
    const float* x     = (const float*)d_in[0];
    const float* h0    = (const float*)d_in[1];
    const float* W_in  = (const float*)d_in[2];
    const float* b_in  = (const float*)d_in[3];
    const float* W_ih  = (const float*)d_in[4];
    const float* b_ih  = (const float*)d_in[5];
    const float* W_hh  = (const float*)d_in[6];
    const float* b_hh  = (const float*)d_in[7];
    const float* W_out = (const float*)d_in[8];
    const float* b_out = (const float*)d_in[9];
    float* out = (float*)d_out;

    float* ws     = (float*)d_ws;
    float* Wc     = ws;                      // 4096 floats
    float* bpre   = ws + 4096;               // 128 floats
    float* hs     = ws + 8192;               // 16,777,216 floats (64 MB)
    float* pooled = ws + 8192 + 16777216;    // 65,536 floats

    prep_kernel<<<1, 128, 0, stream>>>(W_in, b_in, W_ih, b_ih, b_hh, Wc, bpre);
    rnn_kernel<<<512, 512, 0, stream>>>(x, h0, W_hh, Wc, bpre, hs);
    pool_kernel<<<2048, 256, 0, stream>>>(hs, pooled);
    out_kernel<<<512, 256, 0, stream>>>(pooled, W_out, b_out, out);
}

// Round 4
// 288.837 us; speedup vs baseline: 1.2973x; 1.1150x over previous
//
#include <hip/hip_runtime.h>

#define L 256
#define BATCH 512
#define CIN 32
#define RNNIN 64
#define HIDN 128
#define OUTN 512

// ws layout (bytes):
//   Wc     @ 0         (16384)   Wc[j*32+c] = sum_m W_ih[j][m]*W_in[m][c]
//   bpre   @ 16384     (512)     b_ih + b_hh + W_ih@b_in
//   hs     @ 32768     (33554432) bf16 hs[t*65536 + b*128 + j]
//   pooled @ 33587200  (262144)  fp32

__global__ __launch_bounds__(128) void prep_kernel(
    const float* __restrict__ W_in, const float* __restrict__ b_in,
    const float* __restrict__ W_ih, const float* __restrict__ b_ih,
    const float* __restrict__ b_hh,
    float* __restrict__ Wc, float* __restrict__ bpre)
{
    const int j = threadIdx.x;
    float acc[CIN];
#pragma unroll
    for (int c = 0; c < CIN; ++c) acc[c] = 0.f;
    float bs = b_ih[j] + b_hh[j];
    for (int m = 0; m < RNNIN; ++m) {
        float w = W_ih[j * RNNIN + m];
        bs += w * b_in[m];
#pragma unroll
        for (int c = 0; c < CIN; ++c) acc[c] += w * W_in[m * CIN + c];
    }
#pragma unroll
    for (int c = 0; c < CIN; ++c) Wc[j * CIN + c] = acc[c];
    bpre[j] = bs;
}

template <int CTRL>
__device__ __forceinline__ float dpp_add(float v) {
    int sw = __builtin_amdgcn_mov_dpp(__float_as_int(v), CTRL, 0xF, 0xF, true);
    return v + __int_as_float(sw);
}
#define DPP_XOR1 0xB1  // quad_perm(1,0,3,2)
#define DPP_XOR2 0x4E  // quad_perm(2,3,0,1)

// One block = 1 batch row, 256 threads (4 waves), 512 blocks -> 2 blocks/CU.
// Thread (jg = tid>>2, s = tid&3): outputs j0=2jg,j1=2jg+1; k-slice [32s,32s+32),
// x-slice [8s,8s+8). 20 named float4 weights (80 VGPR) -> guaranteed residency
// under launch_bounds(256,2) (256-VGPR budget; grid caps CU at 8 waves anyway).
// Reduce = 2 fused DPP quad-perm stages (s spans a lane-quad). x row staged
// once in 32KB LDS. tanh uses v_rcp (no IEEE division sequence).
__global__ __launch_bounds__(256, 2) void rnn_kernel(
    const float* __restrict__ x, const float* __restrict__ h0,
    const float* __restrict__ Whh, const float* __restrict__ Wc,
    const float* __restrict__ bpre, unsigned short* __restrict__ hs)
{
    const int tid = threadIdx.x;
    const int s = tid & 3;
    const int jg = tid >> 2;           // 0..63
    const int j0 = jg * 2, j1 = j0 + 1;
    const int b = blockIdx.x;

    __shared__ float xlds[L][CIN];     // 32 KB, read-only after init
    __shared__ float hbuf[2][HIDN];    // 1 KB double buffer

    // Weights, chunk-rotated by s so concurrent s-streams hit disjoint banks.
    float4 w0[8], w1[8];
#pragma unroll
    for (int r = 0; r < 8; ++r) {
        int c = (s + r) & 7;
        w0[r] = *(const float4*)(Whh + j0 * HIDN + s * 32 + 4 * c);
        w1[r] = *(const float4*)(Whh + j1 * HIDN + s * 32 + 4 * c);
    }
    float4 g0[2], g1[2];
#pragma unroll
    for (int i = 0; i < 2; ++i) {
        int c = (s + i) & 1;
        g0[i] = *(const float4*)(Wc + j0 * CIN + s * 8 + 4 * c);
        g1[i] = *(const float4*)(Wc + j1 * CIN + s * 8 + 4 * c);
    }
    const float bp0 = bpre[j0], bp1 = bpre[j1];

    // Stage x (32KB) into LDS: coalesced float4 global reads; the stride-32
    // LDS write conflicts are one-time (~1.4K cyc) and irrelevant.
    const float4* xg = (const float4*)(x + (size_t)b * (CIN * L));
#pragma unroll
    for (int it = 0; it < 8; ++it) {
        int i = tid + it * 256;        // float4 index in [0,2048)
        float4 v = xg[i];
        int c = i >> 6;
        int t0 = (i & 63) * 4;
        xlds[t0 + 0][c] = v.x; xlds[t0 + 1][c] = v.y;
        xlds[t0 + 2][c] = v.z; xlds[t0 + 3][c] = v.w;
    }
    if (tid < HIDN) hbuf[0][tid] = h0[b * HIDN + tid];
    __syncthreads();

    const float* hrd[8];
#pragma unroll
    for (int r = 0; r < 8; ++r) hrd[r] = &hbuf[0][s * 32 + 4 * ((s + r) & 7)];
    const int xf0 = s * 8 + 4 * (s & 1);
    const int xf1 = s * 8 + 4 * ((s + 1) & 1);

    unsigned short* hsp = hs + (size_t)b * HIDN + j0;

    auto step = [&](const int p, const int t) {
        float4 xa = *(const float4*)(&xlds[t][xf0]);
        float4 xb = *(const float4*)(&xlds[t][xf1]);
        float A0 = g0[0].x * xa.x + g0[0].y * xa.y + g0[0].z * xa.z + g0[0].w * xa.w;
        float A1 = g0[1].x * xb.x + g0[1].y * xb.y + g0[1].z * xb.z + g0[1].w * xb.w;
        float B0 = g1[0].x * xa.x + g1[0].y * xa.y + g1[0].z * xa.z + g1[0].w * xa.w;
        float B1 = g1[1].x * xb.x + g1[1].y * xb.y + g1[1].z * xb.z + g1[1].w * xb.w;
#pragma unroll
        for (int r = 0; r < 8; ++r) {
            float4 hv = *(const float4*)(hrd[r] + p * HIDN);
            if (r & 1) {
                A1 += w0[r].x * hv.x + w0[r].y * hv.y + w0[r].z * hv.z + w0[r].w * hv.w;
                B1 += w1[r].x * hv.x + w1[r].y * hv.y + w1[r].z * hv.z + w1[r].w * hv.w;
            } else {
                A0 += w0[r].x * hv.x + w0[r].y * hv.y + w0[r].z * hv.z + w0[r].w * hv.w;
                B0 += w1[r].x * hv.x + w1[r].y * hv.y + w1[r].z * hv.z + w1[r].w * hv.w;
            }
        }
        float v0 = A0 + A1;
        float v1 = B0 + B1;
        v0 = dpp_add<DPP_XOR1>(v0); v1 = dpp_add<DPP_XOR1>(v1);
        v0 = dpp_add<DPP_XOR2>(v0); v1 = dpp_add<DPP_XOR2>(v1);
        float pre0 = v0 + bp0, pre1 = v1 + bp1;
        // tanh(z) = 1 - 2/(exp(2z)+1), rcp via v_rcp (1-ulp, fine vs 4e-3 tol)
        float e0 = __expf(2.f * pre0);
        float e1 = __expf(2.f * pre1);
        float hn0 = 1.f - 2.f * __builtin_amdgcn_rcpf(e0 + 1.f);
        float hn1 = 1.f - 2.f * __builtin_amdgcn_rcpf(e1 + 1.f);
        if (s == 0) {
            hbuf[p ^ 1][j0] = hn0;
            hbuf[p ^ 1][j1] = hn1;
            unsigned ua = __float_as_uint(hn0), ub = __float_as_uint(hn1);
            ua = (ua + 0x7fffu + ((ua >> 16) & 1u)) >> 16;   // RNE to bf16
            ub = (ub + 0x7fffu + ((ub >> 16) & 1u)) >> 16;
            *(unsigned*)(hsp + (size_t)t * (BATCH * HIDN)) = ua | (ub << 16);
        }
        __syncthreads();
    };

    for (int t = 0; t < L; t += 2) {
        step(0, t);
        step(1, t + 1);
    }
}

// Upsample 16x16 -> 32x32 (align_corners) + hardswish + mean, fused. bf16 in.
__global__ __launch_bounds__(256) void pool_kernel(
    const unsigned short* __restrict__ hs, float* __restrict__ pooled)
{
    const int b = blockIdx.x >> 2;
    const int j0 = (blockIdx.x & 3) * 32;
    __shared__ float m[L][32];
    for (int i = threadIdx.x; i < L * 8; i += 256) {
        int jo4 = i & 7, t = i >> 3;
        ushort4 v = *(const ushort4*)(hs + (size_t)t * (BATCH * HIDN) + b * HIDN + j0 + jo4 * 4);
        m[t][jo4 * 4 + 0] = __uint_as_float((unsigned)v.x << 16);
        m[t][jo4 * 4 + 1] = __uint_as_float((unsigned)v.y << 16);
        m[t][jo4 * 4 + 2] = __uint_as_float((unsigned)v.z << 16);
        m[t][jo4 * 4 + 3] = __uint_as_float((unsigned)v.w << 16);
    }
    __syncthreads();
    const int jo = threadIdx.x & 31;
    const int sub = threadIdx.x >> 5;
    float acc = 0.f;
#pragma unroll 4
    for (int p = sub; p < 1024; p += 8) {
        int oy = p >> 5, ox = p & 31;
        float ysf = oy * (15.f / 31.f);
        int y0 = (int)ysf; float wy = ysf - (float)y0; int y1 = min(y0 + 1, 15);
        float xsf = ox * (15.f / 31.f);
        int x0 = (int)xsf; float wx = xsf - (float)x0; int x1 = min(x0 + 1, 15);
        float v00 = m[y0 * 16 + x0][jo], v01 = m[y0 * 16 + x1][jo];
        float v10 = m[y1 * 16 + x0][jo], v11 = m[y1 * 16 + x1][jo];
        float v0 = v00 + wx * (v01 - v00);
        float v1 = v10 + wx * (v11 - v10);
        float v = v0 + wy * (v1 - v0);
        float t6 = fminf(fmaxf(v + 3.f, 0.f), 6.f);
        acc += v * t6;
    }
    __shared__ float ps[8][32];
    ps[sub][jo] = acc;
    __syncthreads();
    if (threadIdx.x < 32) {
        float sum = 0.f;
#pragma unroll
        for (int u = 0; u < 8; ++u) sum += ps[u][threadIdx.x];
        pooled[b * HIDN + j0 + threadIdx.x] = sum * (1.f / 6144.f);
    }
}

__global__ __launch_bounds__(256) void out_kernel(
    const float* __restrict__ pooled, const float* __restrict__ W_out,
    const float* __restrict__ b_out, float* __restrict__ out)
{
    const int b = blockIdx.x;
    __shared__ float pv[HIDN];
    if (threadIdx.x < HIDN) pv[threadIdx.x] = pooled[b * HIDN + threadIdx.x];
    __syncthreads();
    for (int o = threadIdx.x; o < OUTN; o += 256) {
        float acc = b_out[o];
#pragma unroll 8
        for (int k = 0; k < HIDN; k += 4) {
            float4 w = *(const float4*)(W_out + o * HIDN + k);
            acc += w.x * pv[k] + w.y * pv[k + 1] + w.z * pv[k + 2] + w.w * pv[k + 3];
        }
        out[b * OUTN + o] = acc;
    }
}

extern "C" void kernel_launch(void* const* d_in, const int* in_sizes, int n_in,
                              void* d_out, int out_size, void* d_ws, size_t ws_size,
                              hipStream_t stream)
{
    const float* x     = (const float*)d_in[0];
    const float* h0    = (const float*)d_in[1];
    const float* W_in  = (const float*)d_in[2];
    const float* b_in  = (const float*)d_in[3];
    const float* W_ih  = (const float*)d_in[4];
    const float* b_ih  = (const float*)d_in[5];
    const float* W_hh  = (const float*)d_in[6];
    const float* b_hh  = (const float*)d_in[7];
    const float* W_out = (const float*)d_in[8];
    const float* b_out = (const float*)d_in[9];
    float* out = (float*)d_out;

    char* wsb = (char*)d_ws;
    float* Wc             = (float*)(wsb);                 // 16384 B
    float* bpre           = (float*)(wsb + 16384);         // 512 B
    unsigned short* hs    = (unsigned short*)(wsb + 32768);// 32 MB bf16
    float* pooled         = (float*)(wsb + 33587200);      // 256 KB

    prep_kernel<<<1, 128, 0, stream>>>(W_in, b_in, W_ih, b_ih, b_hh, Wc, bpre);
    rnn_kernel<<<512, 256, 0, stream>>>(x, h0, W_hh, Wc, bpre, hs);
    pool_kernel<<<2048, 256, 0, stream>>>(hs, pooled);
    out_kernel<<<512, 256, 0, stream>>>(pooled, W_out, b_out, out);
}

// Round 6
// 284.418 us; speedup vs baseline: 1.3175x; 1.0155x over previous
//
#include <hip/hip_runtime.h>

#define L 256
#define BATCH 512
#define CIN 32
#define RNNIN 64
#define HIDN 128
#define OUTN 512

typedef float v2 __attribute__((ext_vector_type(2)));

// ws layout (bytes):
//   Wc     @ 0         (16384)    Wc[j*32+c] = sum_m W_ih[j][m]*W_in[m][c]
//   bpre   @ 16384     (512)      b_ih + b_hh + W_ih@b_in
//   hs     @ 32768     (33554432) bf16 hs[t*65536 + b*128 + j]
//   pooled @ 33587200  (262144)   fp32

__global__ __launch_bounds__(128) void prep_kernel(
    const float* __restrict__ W_in, const float* __restrict__ b_in,
    const float* __restrict__ W_ih, const float* __restrict__ b_ih,
    const float* __restrict__ b_hh,
    float* __restrict__ Wc, float* __restrict__ bpre)
{
    const int j = threadIdx.x;
    float acc[CIN];
#pragma unroll
    for (int c = 0; c < CIN; ++c) acc[c] = 0.f;
    float bs = b_ih[j] + b_hh[j];
    for (int m = 0; m < RNNIN; ++m) {
        float w = W_ih[j * RNNIN + m];
        bs += w * b_in[m];
#pragma unroll
        for (int c = 0; c < CIN; ++c) acc[c] += w * W_in[m * CIN + c];
    }
#pragma unroll
    for (int c = 0; c < CIN; ++c) Wc[j * CIN + c] = acc[c];
    bpre[j] = bs;
}

template <int CTRL>
__device__ __forceinline__ float dpp_add(float v) {
    int sw = __builtin_amdgcn_mov_dpp(__float_as_int(v), CTRL, 0xF, 0xF, true);
    return v + __int_as_float(sw);
}
#define DPP_XOR1 0xB1   // quad_perm(1,0,3,2)
#define DPP_XOR2 0x4E   // quad_perm(2,3,0,1)
// ROW_HALF_MIRROR: lane l <-> lane 7-l within each 8-lane half-row. After
// xor1+xor2 all 4 lanes of a quad hold the identical quad-sum, so the mirror
// adds the OPPOSITE quad's sum into every lane — a direction-proof xor4.
// (R4 bug: row_shr:4 moves data to HIGHER lanes; low quad got 0, half the
// k-sum was dropped.)
#define DPP_HALF_MIRROR 0x141

// One block = 1 batch row, 256 threads (4 waves), 512 blocks -> 2 blocks/CU.
// Thread (jg = tid>>3 in [0,32), s = tid&7): 4 outputs j=4jg..4jg+3,
// k-slice [16s,16s+16), x-slice [4s,4s+4).
// J=4 halves per-step LDS read issue vs R3 (5 b128/thread); dots use packed
// v_pk_fma_f32 (float2); the s-reduce is pure DPP (xor1,xor2,half_mirror).
// h-chunk rotation c=((s>>1)+r)&3 puts the 8 s-streams on disjoint
// bank-quads (conflict-free; same-addr broadcast is free).
__global__ __launch_bounds__(256, 2) void rnn_kernel(
    const float* __restrict__ x, const float* __restrict__ h0,
    const float* __restrict__ Whh, const float* __restrict__ Wc,
    const float* __restrict__ bpre, unsigned short* __restrict__ hs)
{
    const int tid = threadIdx.x;
    const int s = tid & 7;
    const int jg = tid >> 3;           // 0..31
    const int b = blockIdx.x;

    __shared__ float xlds[L][36];      // pad 36: staging conflicts halved; rows 16B-aligned
    __shared__ float hbuf[2][HIDN];

    // Weights: 32+8 v2 pairs (80 floats) + 4 bias
    v2 wh[4][8], wx[4][2];
    float bp[4];
#pragma unroll
    for (int j = 0; j < 4; ++j) {
        const float* wr = Whh + (jg * 4 + j) * HIDN + s * 16;
#pragma unroll
        for (int r = 0; r < 4; ++r) {
            int c = ((s >> 1) + r) & 3;
            float4 v = *(const float4*)(wr + 4 * c);
            wh[j][2 * r]     = (v2){v.x, v.y};
            wh[j][2 * r + 1] = (v2){v.z, v.w};
        }
        float4 g = *(const float4*)(Wc + (jg * 4 + j) * CIN + s * 4);
        wx[j][0] = (v2){g.x, g.y};
        wx[j][1] = (v2){g.z, g.w};
        bp[j] = bpre[jg * 4 + j];
    }

    // Stage x (32KB) into LDS transposed; one-time cost.
    const float4* xg = (const float4*)(x + (size_t)b * (CIN * L));
#pragma unroll
    for (int it = 0; it < 8; ++it) {
        int i = tid + it * 256;        // float4 index in [0,2048)
        float4 v = xg[i];
        int c = i >> 6;
        int t0 = (i & 63) * 4;
        xlds[t0 + 0][c] = v.x; xlds[t0 + 1][c] = v.y;
        xlds[t0 + 2][c] = v.z; xlds[t0 + 3][c] = v.w;
    }
    if (tid < HIDN) hbuf[0][tid] = h0[b * HIDN + tid];
    __syncthreads();

    unsigned short* hsp = hs + (size_t)b * HIDN + jg * 4;

    auto step = [&](const int p, const int t) {
        const float* hb = &hbuf[p][s * 16];
        float4 h4[4];
#pragma unroll
        for (int r = 0; r < 4; ++r)
            h4[r] = *(const float4*)(hb + 4 * (((s >> 1) + r) & 3));
        float4 xv = *(const float4*)(&xlds[t][s * 4]);

        float out[4];
#pragma unroll
        for (int j = 0; j < 4; ++j) {
            v2 acc = wx[j][0] * (v2){xv.x, xv.y};
            acc += wx[j][1] * (v2){xv.z, xv.w};
#pragma unroll
            for (int r = 0; r < 4; ++r) {
                acc += wh[j][2 * r]     * (v2){h4[r].x, h4[r].y};
                acc += wh[j][2 * r + 1] * (v2){h4[r].z, h4[r].w};
            }
            float a = acc.x + acc.y + bp[j];
            a = dpp_add<DPP_XOR1>(a);
            a = dpp_add<DPP_XOR2>(a);
            a = dpp_add<DPP_HALF_MIRROR>(a);  // all 8 s-lanes now hold full sum
            // tanh(z) = 1 - 2/(exp(2z)+1)
            float e = __expf(2.f * a);
            out[j] = 1.f - 2.f * __builtin_amdgcn_rcpf(e + 1.f);
        }
        if (s == 0) {
            *(float4*)(&hbuf[p ^ 1][jg * 4]) = make_float4(out[0], out[1], out[2], out[3]);
            unsigned u[4];
#pragma unroll
            for (int j = 0; j < 4; ++j) {
                unsigned q = __float_as_uint(out[j]);
                u[j] = (q + 0x7fffu + ((q >> 16) & 1u)) >> 16;  // RNE to bf16
            }
            uint2 pk;
            pk.x = u[0] | (u[1] << 16);
            pk.y = u[2] | (u[3] << 16);
            *(uint2*)(hsp + (size_t)t * (BATCH * HIDN)) = pk;
        }
        __syncthreads();
    };

    for (int t = 0; t < L; t += 2) {
        step(0, t);
        step(1, t + 1);
    }
}

// Upsample 16x16 -> 32x32 (align_corners) + hardswish + mean, fused. bf16 in.
__global__ __launch_bounds__(256) void pool_kernel(
    const unsigned short* __restrict__ hs, float* __restrict__ pooled)
{
    const int b = blockIdx.x >> 2;
    const int j0 = (blockIdx.x & 3) * 32;
    __shared__ float m[L][32];
    for (int i = threadIdx.x; i < L * 8; i += 256) {
        int jo4 = i & 7, t = i >> 3;
        ushort4 v = *(const ushort4*)(hs + (size_t)t * (BATCH * HIDN) + b * HIDN + j0 + jo4 * 4);
        m[t][jo4 * 4 + 0] = __uint_as_float((unsigned)v.x << 16);
        m[t][jo4 * 4 + 1] = __uint_as_float((unsigned)v.y << 16);
        m[t][jo4 * 4 + 2] = __uint_as_float((unsigned)v.z << 16);
        m[t][jo4 * 4 + 3] = __uint_as_float((unsigned)v.w << 16);
    }
    __syncthreads();
    const int jo = threadIdx.x & 31;
    const int sub = threadIdx.x >> 5;
    float acc = 0.f;
#pragma unroll 4
    for (int p = sub; p < 1024; p += 8) {
        int oy = p >> 5, ox = p & 31;
        float ysf = oy * (15.f / 31.f);
        int y0 = (int)ysf; float wy = ysf - (float)y0; int y1 = min(y0 + 1, 15);
        float xsf = ox * (15.f / 31.f);
        int x0 = (int)xsf; float wx = xsf - (float)x0; int x1 = min(x0 + 1, 15);
        float v00 = m[y0 * 16 + x0][jo], v01 = m[y0 * 16 + x1][jo];
        float v10 = m[y1 * 16 + x0][jo], v11 = m[y1 * 16 + x1][jo];
        float v0 = v00 + wx * (v01 - v00);
        float v1 = v10 + wx * (v11 - v10);
        float v = v0 + wy * (v1 - v0);
        float t6 = fminf(fmaxf(v + 3.f, 0.f), 6.f);
        acc += v * t6;
    }
    __shared__ float ps[8][32];
    ps[sub][jo] = acc;
    __syncthreads();
    if (threadIdx.x < 32) {
        float sum = 0.f;
#pragma unroll
        for (int u = 0; u < 8; ++u) sum += ps[u][threadIdx.x];
        pooled[b * HIDN + j0 + threadIdx.x] = sum * (1.f / 6144.f);
    }
}

__global__ __launch_bounds__(256) void out_kernel(
    const float* __restrict__ pooled, const float* __restrict__ W_out,
    const float* __restrict__ b_out, float* __restrict__ out)
{
    const int b = blockIdx.x;
    __shared__ float pv[HIDN];
    if (threadIdx.x < HIDN) pv[threadIdx.x] = pooled[b * HIDN + threadIdx.x];
    __syncthreads();
    for (int o = threadIdx.x; o < OUTN; o += 256) {
        float acc = b_out[o];
#pragma unroll 8
        for (int k = 0; k < HIDN; k += 4) {
            float4 w = *(const float4*)(W_out + o * HIDN + k);
            acc += w.x * pv[k] + w.y * pv[k + 1] + w.z * pv[k + 2] + w.w * pv[k + 3];
        }
        out[b * OUTN + o] = acc;
    }
}

extern "C" void kernel_launch(void* const* d_in, const int* in_sizes, int n_in,
                              void* d_out, int out_size, void* d_ws, size_t ws_size,
                              hipStream_t stream)
{
    const float* x     = (const float*)d_in[0];
    const float* h0    = (const float*)d_in[1];
    const float* W_in  = (const float*)d_in[2];
    const float* b_in  = (const float*)d_in[3];
    const float* W_ih  = (const float*)d_in[4];
    const float* b_ih  = (const float*)d_in[5];
    const float* W_hh  = (const float*)d_in[6];
    const float* b_hh  = (const float*)d_in[7];
    const float* W_out = (const float*)d_in[8];
    const float* b_out = (const float*)d_in[9];
    float* out = (float*)d_out;

    char* wsb = (char*)d_ws;
    float* Wc          = (float*)(wsb);                  // 16384 B
    float* bpre        = (float*)(wsb + 16384);          // 512 B
    unsigned short* hs = (unsigned short*)(wsb + 32768); // 32 MB bf16
    float* pooled      = (float*)(wsb + 33587200);       // 256 KB

    prep_kernel<<<1, 128, 0, stream>>>(W_in, b_in, W_ih, b_ih, b_hh, Wc, bpre);
    rnn_kernel<<<512, 256, 0, stream>>>(x, h0, W_hh, Wc, bpre, hs);
    pool_kernel<<<2048, 256, 0, stream>>>(hs, pooled);
    out_kernel<<<512, 256, 0, stream>>>(pooled, W_out, b_out, out);
}